// Round 5
// baseline (603.407 us; speedup 1.0000x reference)
//
#include <hip/hip_runtime.h>
#include <math.h>

// DisplacementTensors: per-edge radial-MLP + segment-sum to nodes + per-node linear map.
// N_NODES=50000, N_EDGES=1600000, DIM_A=DIM_V=32, R0=5, LEAK=0.1
//
// Round 5: round 4 was latency-bound at 2 blocks/CU (53.7KB LDS) with 768
// uniform ds_read_b128 weight broadcasts per window on the critical path.
// Fix: weights are wave-uniform constants -> read them straight from global
// with fully-unrolled constant indices; the compiler scalarizes these into
// s_load (constant cache, SGPR operands for v_fmac). Kills ~85% of DS traffic
// and 12.5KB of LDS -> 40KB/block -> 4 blocks/CU (2x occupancy). Also: the
// radial coefficients 1+(k>>1) have only 8 distinct values -> 8 sincos, not 16.
//
// d_out layout: A_a [50000*32] floats, then out_v [50000*32*3] floats.
// ws layout: counts[NN] | offsets[NN+1] | rank[NE] | edge_ids[NE]  (13.2 MB)

#define NN 50000
#define NE 1600000
#define DA 32
#define PI_R0 0.62831853071795864769f  // pi / 5

__device__ __forceinline__ void wsync() {
    // intra-wave LDS handoff: wave is lockstep; drain the DS queue so
    // cross-lane reads see this wave's writes.
    asm volatile("s_waitcnt lgkmcnt(0)" ::: "memory");
}

// ---------------- CSR build ----------------

__global__ __launch_bounds__(256) void k_hist(const int* __restrict__ src,
                                              int* __restrict__ counts,
                                              int* __restrict__ rank) {
    const int e = blockIdx.x * 256 + threadIdx.x;   // grid exactly NE/256
    rank[e] = atomicAdd(&counts[src[e]], 1);
}

__global__ __launch_bounds__(256) void k_scan(const int* __restrict__ counts,
                                              int* __restrict__ offsets) {
    __shared__ int part[256];
    const int CH = (NN + 255) / 256;   // 196
    const int t = threadIdx.x;
    const int base = t * CH;
    int s = 0;
    for (int k = 0; k < CH; ++k) { const int idx = base + k; if (idx < NN) s += counts[idx]; }
    part[t] = s;
    __syncthreads();
    if (t == 0) {
        int run = 0;
        for (int k = 0; k < 256; ++k) { const int v = part[k]; part[k] = run; run += v; }
    }
    __syncthreads();
    int run = part[t];
    for (int k = 0; k < CH; ++k) {
        const int idx = base + k;
        if (idx < NN) { offsets[idx] = run; run += counts[idx]; }
    }
    if (t == 255) offsets[NN] = run;   // total == NE
}

__global__ __launch_bounds__(256) void k_scatter(const int* __restrict__ src,
                                                 const int* __restrict__ offsets,
                                                 const int* __restrict__ rank,
                                                 int* __restrict__ edge_ids) {
    const int e = blockIdx.x * 256 + threadIdx.x;
    edge_ids[offsets[src[e]] + rank[e]] = e;
}

// ---------------- phase A: per-lane MLP over CSR windows + segmented flush ----------------
// block = 256 = 4 waves; wave handles 64 consecutive CSR slots (edges sorted
// by src). Per-lane MLP with SCALAR (s_load) weight reads at uniform constant
// addresses. Wave transposes rad+rv via its own padded LDS region (no block
// barrier), serial segmented reduce (node id wave-uniform), atomic flush.

__global__ __launch_bounds__(256, 4) void dt_window(
    const float* __restrict__ r_ij,
    const float* __restrict__ res_emb,
    const int*   __restrict__ src,
    const int*   __restrict__ dst,
    const int*   __restrict__ edge_ids,
    const float* __restrict__ W1, const float* __restrict__ b1,
    const float* __restrict__ W2, const float* __restrict__ b2,
    const float* __restrict__ W3,
    float* __restrict__ A_a,    // [NN][32]  (accumulates, pre-zeroed)
    float* __restrict__ out_v)  // [NN][32][3] (accumulates raw A_v, pre-zeroed)
{
    __shared__ float  rad_lds[4][64][36];   // [wave][slot][dim], pad 36: banks (l*4+i)%32, conflict-free
    __shared__ float4 rvn_lds[4][64];       // [wave][slot] = (vx, vy, vz, bits(node))

    const int tid  = threadIdx.x;
    const int wv   = tid >> 6;
    const int lane = tid & 63;
    const int slot = blockIdx.x * 256 + tid;   // grid exactly NE/256

    const int eid  = edge_ids[slot];
    const int node = src[eid];

    const float rx = r_ij[eid*3 + 0];
    const float ry = r_ij[eid*3 + 1];
    const float rz = r_ij[eid*3 + 2];
    const float dist = sqrtf(rx*rx + ry*ry + rz*rz);

    // radial encode: coeffs 1+(k>>1) -> only 8 distinct phases
    float xa[DA], xb[DA];
    #pragma unroll
    for (int m = 0; m < 8; ++m) {
        float sph, cph;
        __sincosf(PI_R0 * (float)(m + 1) * dist, &sph, &cph);
        xa[2*m]      = cph;  xa[2*m + 1]      = cph;
        xa[16 + 2*m] = sph;  xa[16 + 2*m + 1] = sph;
    }
    // gather res_emb[dst] (random 128B row, L2-resident)
    const float4* er = (const float4*)(res_emb + (size_t)dst[eid] * DA);
    #pragma unroll
    for (int q = 0; q < 8; ++q) {
        const float4 v = er[q];
        xa[q*4+0] += v.x; xa[q*4+1] += v.y; xa[q*4+2] += v.z; xa[q*4+3] += v.w;
    }

    // layer 1: xb = leaky(W1 xa + b1)  — weight addresses are uniform constants
    // => backend scalarizes to s_load; v_fmac takes the SGPR operand directly.
    #pragma unroll
    for (int i = 0; i < DA; ++i) {
        float acc = b1[i];
        #pragma unroll
        for (int j4 = 0; j4 < 8; ++j4) {
            const float4 w = *(const float4*)&W1[i*DA + j4*4];
            acc += w.x*xa[j4*4+0] + w.y*xa[j4*4+1] + w.z*xa[j4*4+2] + w.w*xa[j4*4+3];
        }
        xb[i] = (acc >= 0.0f) ? acc : 0.1f * acc;
    }
    // layer 2: xa = leaky(W2 xb + b2)
    #pragma unroll
    for (int i = 0; i < DA; ++i) {
        float acc = b2[i];
        #pragma unroll
        for (int j4 = 0; j4 < 8; ++j4) {
            const float4 w = *(const float4*)&W2[i*DA + j4*4];
            acc += w.x*xb[j4*4+0] + w.y*xb[j4*4+1] + w.z*xb[j4*4+2] + w.w*xb[j4*4+3];
        }
        xa[i] = (acc >= 0.0f) ? acc : 0.1f * acc;
    }
    // layer 3: xb = W3 xa
    #pragma unroll
    for (int i = 0; i < DA; ++i) {
        float acc = 0.0f;
        #pragma unroll
        for (int j4 = 0; j4 < 8; ++j4) {
            const float4 w = *(const float4*)&W3[i*DA + j4*4];
            acc += w.x*xa[j4*4+0] + w.y*xa[j4*4+1] + w.z*xa[j4*4+2] + w.w*xa[j4*4+3];
        }
        xb[i] = acc;
    }

    // equivariant gate: rv = q * tanh(|q|)/|q|, q = r * (7/5)
    const float qx = rx*1.4f, qy = ry*1.4f, qz = rz*1.4f;
    const float nq = sqrtf(qx*qx + qy*qy + qz*qz);
    const float e2 = __expf(2.0f * nq);
    const float sc = (nq > 0.0f)
        ? (e2 - 1.0f) * __builtin_amdgcn_rcpf((e2 + 1.0f) * nq)
        : 0.0f;

    // stash this lane's rad row + (rv, node) into the wave's LDS region
    float* rrow = rad_lds[wv][lane];
    #pragma unroll
    for (int q = 0; q < 8; ++q) {
        *(float4*)&rrow[q*4] = make_float4(xb[q*4+0], xb[q*4+1], xb[q*4+2], xb[q*4+3]);
    }
    rvn_lds[wv][lane] = make_float4(qx*sc, qy*sc, qz*sc, __int_as_float(node));
    wsync();   // wave-local region only; no block barrier needed

    // ---- serial segmented reduce over the wave's 64 slots ----
    // lane = (p<<5)|i; every lane accumulates all 4 sums for dim i;
    // at flush p=0 writes {A_a, v0}, p=1 writes {v1, v2}.
    const int p = lane >> 5;
    const int i = lane & 31;

    float accA = 0.0f, a0 = 0.0f, a1 = 0.0f, a2 = 0.0f;
    int cur = __float_as_int(rvn_lds[wv][0].w);

    for (int l = 0; l < 64; ++l) {
        const float4 rvn = rvn_lds[wv][l];          // uniform b128 broadcast
        const int nd = __float_as_int(rvn.w);       // wave-uniform
        const float rd = rad_lds[wv][l][i];         // conflict-free, 2-way p-broadcast
        if (nd != cur) {                            // wave-uniform branch
            if (p == 0) {
                atomicAdd(&A_a[cur*DA + i], accA);
                atomicAdd(&out_v[(cur*DA + i)*3 + 0], a0);
            } else {
                atomicAdd(&out_v[(cur*DA + i)*3 + 1], a1);
                atomicAdd(&out_v[(cur*DA + i)*3 + 2], a2);
            }
            accA = a0 = a1 = a2 = 0.0f;
            cur = nd;
        }
        accA += rd;
        a0 += rd * rvn.x;
        a1 += rd * rvn.y;
        a2 += rd * rvn.z;
    }
    if (p == 0) {
        atomicAdd(&A_a[cur*DA + i], accA);
        atomicAdd(&out_v[(cur*DA + i)*3 + 0], a0);
    } else {
        atomicAdd(&out_v[(cur*DA + i)*3 + 1], a1);
        atomicAdd(&out_v[(cur*DA + i)*3 + 2], a2);
    }
}

// ---------------- phase B: out_v[n][v][d] = sum_a Wv[v][a] * A_v[n][a][d], in place ----------------

__global__ __launch_bounds__(256) void dt_node(
    const float* __restrict__ Wv,
    float* Av_out)   // aliased read+write, deliberately NOT restrict
{
    __shared__ float sWv[DA*DA];
    for (int i = threadIdx.x; i < DA*DA; i += 256) sWv[i] = Wv[i];
    __syncthreads();

    const int t = blockIdx.x * 256 + threadIdx.x;   // grid exactly NN*32/256
    const int n = t >> 5;
    const int v = t & 31;

    const float* av = Av_out + (size_t)n * (DA*3);
    float o0 = 0.0f, o1 = 0.0f, o2 = 0.0f;
    #pragma unroll
    for (int a = 0; a < DA; ++a) {
        const float w = sWv[v*DA + a];
        o0 += w * av[a*3 + 0];
        o1 += w * av[a*3 + 1];
        o2 += w * av[a*3 + 2];
    }
    __syncthreads();   // all loads of this block's nodes complete before any store
    float* o = Av_out + (size_t)n * (DA*3) + v*3;
    o[0] = o0; o[1] = o1; o[2] = o2;
}

// ---------------- fallback path (atomic version, used only if ws too small) ----------------

__global__ __launch_bounds__(256) void dt_edge_atomic(
    const float* __restrict__ r_ij, const float* __restrict__ res_emb,
    const int* __restrict__ src, const int* __restrict__ dst,
    const float* __restrict__ W1, const float* __restrict__ b1,
    const float* __restrict__ W2, const float* __restrict__ b2,
    const float* __restrict__ W3,
    float* __restrict__ A_a, float* __restrict__ A_v)
{
    const int e = blockIdx.x * 256 + threadIdx.x;
    const float rx = r_ij[(size_t)e*3+0], ry = r_ij[(size_t)e*3+1], rz = r_ij[(size_t)e*3+2];
    const float dist = sqrtf(rx*rx + ry*ry + rz*rz);
    float xa[DA], xb[DA];
    #pragma unroll
    for (int m = 0; m < 8; ++m) {
        float sph, cph; __sincosf(PI_R0 * (float)(m + 1) * dist, &sph, &cph);
        xa[2*m] = cph; xa[2*m+1] = cph; xa[16+2*m] = sph; xa[16+2*m+1] = sph;
    }
    const int d = dst[e];
    const float4* er = (const float4*)(res_emb + (size_t)d * DA);
    #pragma unroll
    for (int q = 0; q < 8; ++q) {
        const float4 v = er[q];
        xa[q*4+0]+=v.x; xa[q*4+1]+=v.y; xa[q*4+2]+=v.z; xa[q*4+3]+=v.w;
    }
    #pragma unroll
    for (int i = 0; i < DA; ++i) {
        float acc = b1[i];
        #pragma unroll
        for (int j = 0; j < DA; ++j) acc += xa[j] * W1[i*DA+j];
        xb[i] = (acc >= 0.0f) ? acc : 0.1f*acc;
    }
    #pragma unroll
    for (int i = 0; i < DA; ++i) {
        float acc = b2[i];
        #pragma unroll
        for (int j = 0; j < DA; ++j) acc += xb[j] * W2[i*DA+j];
        xa[i] = (acc >= 0.0f) ? acc : 0.1f*acc;
    }
    #pragma unroll
    for (int i = 0; i < DA; ++i) {
        float acc = 0.0f;
        #pragma unroll
        for (int j = 0; j < DA; ++j) acc += xa[j] * W3[i*DA+j];
        xb[i] = acc;
    }
    const float qx = rx*1.4f, qy = ry*1.4f, qz = rz*1.4f;
    const float nq = sqrtf(qx*qx+qy*qy+qz*qz);
    const float sc = (nq > 0.0f) ? (tanhf(nq)/nq) : 0.0f;
    const float vx = qx*sc, vy = qy*sc, vz = qz*sc;
    const int s = src[e];
    float* pa = A_a + (size_t)s * DA;
    float* pv = A_v + (size_t)s * (DA*3);
    #pragma unroll
    for (int i = 0; i < DA; ++i) atomicAdd(&pa[i], xb[i]);
    #pragma unroll
    for (int i = 0; i < DA; ++i) {
        atomicAdd(&pv[i*3+0], xb[i]*vx);
        atomicAdd(&pv[i*3+1], xb[i]*vy);
        atomicAdd(&pv[i*3+2], xb[i]*vz);
    }
}

// ---------------- launch ----------------

extern "C" void kernel_launch(void* const* d_in, const int* in_sizes, int n_in,
                              void* d_out, int out_size, void* d_ws, size_t ws_size,
                              hipStream_t stream) {
    const float* r_ij    = (const float*)d_in[0];
    const float* res_emb = (const float*)d_in[1];
    const int*   src     = (const int*)d_in[2];
    const int*   dst     = (const int*)d_in[3];
    const float* W1      = (const float*)d_in[4];
    const float* b1      = (const float*)d_in[5];
    const float* W2      = (const float*)d_in[6];
    const float* b2      = (const float*)d_in[7];
    const float* W3      = (const float*)d_in[8];
    const float* Wv      = (const float*)d_in[9];

    float* A_a   = (float*)d_out;                    // [NN][32]
    float* out_v = (float*)d_out + (size_t)NN * DA;  // [NN][32][3]

    const size_t need = ((size_t)NN + (size_t)(NN + 1) + (size_t)NE + (size_t)NE) * sizeof(int);

    // output is accumulated into -> must be zeroed every call
    hipMemsetAsync(d_out, 0, (size_t)out_size * sizeof(float), stream);

    if (ws_size >= need) {
        int* counts   = (int*)d_ws;
        int* offsets  = counts + NN;
        int* rank     = offsets + NN + 1;
        int* edge_ids = rank + NE;

        hipMemsetAsync(counts, 0, (size_t)NN * sizeof(int), stream);
        k_hist   <<<NE / 256, 256, 0, stream>>>(src, counts, rank);
        k_scan   <<<1, 256, 0, stream>>>(counts, offsets);
        k_scatter<<<NE / 256, 256, 0, stream>>>(src, offsets, rank, edge_ids);
        dt_window<<<NE / 256, 256, 0, stream>>>(r_ij, res_emb, src, dst, edge_ids,
                                                W1, b1, W2, b2, W3, A_a, out_v);
        dt_node  <<<(NN * DA) / 256, 256, 0, stream>>>(Wv, out_v);
    } else {
        dt_edge_atomic<<<NE / 256, 256, 0, stream>>>(r_ij, res_emb, src, dst,
                                                     W1, b1, W2, b2, W3, A_a, out_v);
        dt_node<<<(NN * DA) / 256, 256, 0, stream>>>(Wv, out_v);
    }
}